// Round 1
// baseline (1267.481 us; speedup 1.0000x reference)
//
#include <hip/hip_runtime.h>
#include <math.h>

#define N1 10000
#define N2 5000
#define DIN 30
#define DZ 32

// workspace layout (float offsets)
#define OFF_K    0        // K_proj [N1][32]
#define OFF_F    320000   // lm_feature padded [N1][32]
#define OFF_Q    640000   // Q_proj [N2][32]
#define OFF_ASUM 800000   // asum [N2]
#define OFF_AGG  805000   // aggvec [N2][32]
#define OFF_RED  965000   // rsum[32], dvec[32], ds_sum[1]
#define OFF_R01  965072   // router_0[32], router_1[32]

__device__ __forceinline__ float softplus_f(float x) {
  return fmaxf(x, 0.f) + log1pf(__expf(-fabsf(x)));
}

// K_proj[j][z] = dot(lm_X[j], Wk[z]); F[j][z] = lm_feature
__global__ __launch_bounds__(256) void k_prep_lm(const float* __restrict__ lm_X,
    const float* __restrict__ lm_Y, const float* __restrict__ Wk,
    float* __restrict__ Kp, float* __restrict__ Fp) {
  int idx = blockIdx.x * 256 + threadIdx.x;
  if (idx >= N1 * DZ) return;
  int j = idx >> 5, z = idx & 31;
  const float* xr = lm_X + j * DIN;
  const float* wr = Wk + z * DIN;
  float s = 0.f;
#pragma unroll
  for (int k = 0; k < DIN; ++k) s += xr[k] * wr[k];
  Kp[idx] = s;
  Fp[idx] = (z < DIN) ? xr[z] : lm_Y[j * 2 + (z - DIN)];
}

// Q_proj[i][z] = dot(tg_X[i], Wq[z])
__global__ __launch_bounds__(256) void k_prep_tg(const float* __restrict__ tg_X,
    const float* __restrict__ Wq, float* __restrict__ Qp) {
  int idx = blockIdx.x * 256 + threadIdx.x;
  if (idx >= N2 * DZ) return;
  int i = idx >> 5, z = idx & 31;
  const float* xr = tg_X + i * DIN;
  const float* wr = Wq + z * DIN;
  float s = 0.f;
#pragma unroll
  for (int k = 0; k < DIN; ++k) s += xr[k] * wr[k];
  Qp[idx] = s;
}

// reductions over landmarks: rsum[32] (col-sum of F), dvec[32] (delay_score @ F), ds_sum
__global__ __launch_bounds__(256) void k_reduce_lm(const float* __restrict__ Fp,
    const float* __restrict__ lm_delay, const float* __restrict__ g1p,
    const float* __restrict__ ap, const float* __restrict__ bp,
    float* __restrict__ red) {
  const int z = threadIdx.x & 31, jg = threadIdx.x >> 5;
  const float a = ap[0], b = bp[0], g1 = g1p[0];
  float rs = 0.f, dv = 0.f, dss = 0.f;
  for (int j = blockIdx.x * 8 + jg; j < N1; j += 80 * 8) {
    float f = Fp[j * DZ + z];
    float ds = __expf(-g1 * (a * lm_delay[j] + b));
    rs += f; dv += ds * f;
    if (z == 0) dss += ds;
  }
  __shared__ float sb0[8][32], sb1[8][32], sd[8];
  sb0[jg][z] = rs; sb1[jg][z] = dv;
  if (z == 0) sd[jg] = dss;
  __syncthreads();
  if (threadIdx.x < 32) {
    float t0 = 0.f, t1 = 0.f;
#pragma unroll
    for (int g = 0; g < 8; ++g) { t0 += sb0[g][threadIdx.x]; t1 += sb1[g][threadIdx.x]; }
    atomicAdd(&red[threadIdx.x], t0);
    atomicAdd(&red[32 + threadIdx.x], t1);
  } else if (threadIdx.x == 32) {
    float t = 0.f;
#pragma unroll
    for (int g = 0; g < 8; ++g) t += sd[g];
    atomicAdd(&red[64], t);
  }
}

// fused attention: per wave, 2 target rows; pass A: Z = sum_j exp(s); pass B: t = exp(exp(s)/Z),
// asum = sum t, aggvec = sum t * F[j]
__global__ __launch_bounds__(256) void k_attn(const float* __restrict__ Kp,
    const float* __restrict__ Fp, const float* __restrict__ Qp,
    float* __restrict__ asum, float* __restrict__ aggvec) {
  const int lane = threadIdx.x & 63;
  const int wid = threadIdx.x >> 6;
  const int i0 = (blockIdx.x * 4 + wid) * 2;
  const int i1 = i0 + 1;
  const float rtemp = 0.17677669529663687f;  // 1/sqrt(32)

  float4 q0[8], q1[8];
  const float4* Q0 = (const float4*)(Qp + i0 * DZ);
  const float4* Q1 = (const float4*)(Qp + i1 * DZ);
#pragma unroll
  for (int m = 0; m < 8; ++m) { q0[m] = Q0[m]; q1[m] = Q1[m]; }

  // pass A: softmax denominators (shift-invariant; scores bounded, so no max needed)
  float zs0 = 0.f, zs1 = 0.f;
  for (int j = lane; j < N1; j += 64) {
    const float4* K4 = (const float4*)(Kp + j * DZ);
    float s0 = 0.f, s1 = 0.f;
#pragma unroll
    for (int m = 0; m < 8; ++m) {
      float4 k = K4[m];
      s0 += q0[m].x * k.x + q0[m].y * k.y + q0[m].z * k.z + q0[m].w * k.w;
      s1 += q1[m].x * k.x + q1[m].y * k.y + q1[m].z * k.z + q1[m].w * k.w;
    }
    zs0 += __expf(s0 * rtemp);
    zs1 += __expf(s1 * rtemp);
  }
#pragma unroll
  for (int m = 1; m < 64; m <<= 1) {
    zs0 += __shfl_xor(zs0, m, 64);
    zs1 += __shfl_xor(zs1, m, 64);
  }
  const float invZ0 = 1.f / zs0, invZ1 = 1.f / zs1;

  // pass B
  float as0 = 0.f, as1 = 0.f;
  float acc0[DZ], acc1[DZ];
#pragma unroll
  for (int z = 0; z < DZ; ++z) { acc0[z] = 0.f; acc1[z] = 0.f; }
  for (int j = lane; j < N1; j += 64) {
    const float4* K4 = (const float4*)(Kp + j * DZ);
    float s0 = 0.f, s1 = 0.f;
#pragma unroll
    for (int m = 0; m < 8; ++m) {
      float4 k = K4[m];
      s0 += q0[m].x * k.x + q0[m].y * k.y + q0[m].z * k.z + q0[m].w * k.w;
      s1 += q1[m].x * k.x + q1[m].y * k.y + q1[m].z * k.z + q1[m].w * k.w;
    }
    float t0 = __expf(__expf(s0 * rtemp) * invZ0);
    float t1 = __expf(__expf(s1 * rtemp) * invZ1);
    as0 += t0; as1 += t1;
    const float4* F4 = (const float4*)(Fp + j * DZ);
#pragma unroll
    for (int m = 0; m < 8; ++m) {
      float4 f = F4[m];
      acc0[4 * m + 0] += t0 * f.x; acc0[4 * m + 1] += t0 * f.y;
      acc0[4 * m + 2] += t0 * f.z; acc0[4 * m + 3] += t0 * f.w;
      acc1[4 * m + 0] += t1 * f.x; acc1[4 * m + 1] += t1 * f.y;
      acc1[4 * m + 2] += t1 * f.z; acc1[4 * m + 3] += t1 * f.w;
    }
  }
#pragma unroll
  for (int m = 1; m < 64; m <<= 1) {
    as0 += __shfl_xor(as0, m, 64);
    as1 += __shfl_xor(as1, m, 64);
  }
#pragma unroll
  for (int z = 0; z < DZ; ++z) {
#pragma unroll
    for (int m = 1; m < 64; m <<= 1) {
      acc0[z] += __shfl_xor(acc0[z], m, 64);
      acc1[z] += __shfl_xor(acc1[z], m, 64);
    }
  }
  if (lane == 0) { asum[i0] = as0; asum[i1] = as1; }
#pragma unroll
  for (int z = 0; z < DZ; ++z) {
    if (lane == z) {
      aggvec[i0 * DZ + z] = acc0[z];
      aggvec[i1 * DZ + z] = acc1[z];
    }
  }
}

// router_0 and router_1 (tiny)
__global__ void k_router(const float* __restrict__ red, float* __restrict__ r01,
    const float* __restrict__ W1, const float* __restrict__ b1) {
  __shared__ float s_aggr[DZ];
  const int z = threadIdx.x;
  const float r0 = red[z] / (float)N1;
  const float deg_r = 1.f + red[64] + 1e-12f;
  s_aggr[z] = (r0 + red[32 + z]) / deg_r;
  r01[z] = r0;
  __syncthreads();
  float acc = b1[z];
#pragma unroll
  for (int k = 0; k < DZ; ++k) acc += W1[z * DZ + k] * s_aggr[k];
  r01[DZ + z] = acc;
}

// per-target tail: two 32x32 matvecs + heads
__global__ __launch_bounds__(256) void k_final(
    const float* __restrict__ tg_X, const float* __restrict__ tg_delay,
    const float* __restrict__ asum, const float* __restrict__ aggvec,
    const float* __restrict__ r01,
    const float* __restrict__ W1, const float* __restrict__ b1,
    const float* __restrict__ W2, const float* __restrict__ b2,
    const float* __restrict__ Wg, const float* __restrict__ bg,
    const float* __restrict__ Wa, const float* __restrict__ ba,
    const float* __restrict__ g2p, const float* __restrict__ g3p,
    const float* __restrict__ ap, const float* __restrict__ bp,
    float* __restrict__ out) {
  __shared__ float s_a[8][DZ], s_t1[8][DZ], s_t2[8][DZ];
  const int z = threadIdx.x & 31, li = threadIdx.x >> 5;
  const int i = blockIdx.x * 8 + li;
  const float a = ap[0], b = bp[0], g2 = g2p[0], g3 = g3p[0];
  const float td = tg_delay[i];
  const float rt0 = __expf(-g2 * (a * td + b));
  const float rt1 = __expf(-g3 * (a * td + b));
  const float tgx = (z < DIN) ? tg_X[i * DIN + z] : 0.f;
  const float deg = 1.f + asum[i] + rt0 + 1e-12f;
  s_a[li][z] = (tgx + aggvec[i * DZ + z] + rt0 * r01[z]) / deg;
  __syncthreads();
  float t1 = b1[z];
#pragma unroll
  for (int k = 0; k < DZ; ++k) t1 += W1[z * DZ + k] * s_a[li][k];
  s_t1[li][z] = t1;
  __syncthreads();
  s_a[li][z] = (t1 + rt1 * r01[DZ + z]) / (1.f + rt1 + 1e-12f);
  __syncthreads();
  float t2 = b2[z];
#pragma unroll
  for (int k = 0; k < DZ; ++k) t2 += W2[z * DZ + k] * s_a[li][k];
  s_t2[li][z] = t2;
  __syncthreads();
  if (z < 5) {
    float og = bg[z];
#pragma unroll
    for (int k = 0; k < DZ; ++k) og += Wg[z * 64 + k] * s_t1[li][k];
#pragma unroll
    for (int k = 0; k < DZ; ++k) og += Wg[z * 64 + DZ + k] * s_t2[li][k];
    if (z == 0)      out[2 * i] = og;
    else if (z == 1) out[2 * i + 1] = og;
    else if (z == 2) out[10000 + i] = softplus_f(og);
    else if (z == 3) out[15000 + i] = softplus_f(og) + 1.f;
    else             out[20000 + i] = softplus_f(og);
  } else if (z >= 8 && z < 13) {
    const int h = z - 8;
    float oa = ba[h];
#pragma unroll
    for (int k = 0; k < DIN; ++k) oa += Wa[h * DIN + k] * tg_X[i * DIN + k];
    if (h == 0)      out[25000 + 2 * i] = oa;
    else if (h == 1) out[25000 + 2 * i + 1] = oa;
    else if (h == 2) out[35000 + i] = softplus_f(oa);
    else if (h == 3) out[40000 + i] = softplus_f(oa) + 1.f;
    else             out[45000 + i] = softplus_f(oa);
  }
}

extern "C" void kernel_launch(void* const* d_in, const int* in_sizes, int n_in,
                              void* d_out, int out_size, void* d_ws, size_t ws_size,
                              hipStream_t stream) {
  const float* lm_X    = (const float*)d_in[0];
  const float* lm_Y    = (const float*)d_in[1];
  const float* tg_X    = (const float*)d_in[2];
  const float* lm_delay= (const float*)d_in[4];
  const float* tg_delay= (const float*)d_in[5];
  const float* Wq      = (const float*)d_in[6];
  const float* Wk      = (const float*)d_in[7];
  const float* g1      = (const float*)d_in[9];
  const float* g2      = (const float*)d_in[10];
  const float* g3      = (const float*)d_in[11];
  const float* al      = (const float*)d_in[12];
  const float* be      = (const float*)d_in[13];
  const float* W1      = (const float*)d_in[14];
  const float* b1      = (const float*)d_in[15];
  const float* W2      = (const float*)d_in[16];
  const float* b2      = (const float*)d_in[17];
  const float* Wg      = (const float*)d_in[18];
  const float* bg      = (const float*)d_in[19];
  const float* Wa      = (const float*)d_in[20];
  const float* ba      = (const float*)d_in[21];
  float* out = (float*)d_out;
  float* ws  = (float*)d_ws;

  hipMemsetAsync(ws + OFF_RED, 0, 65 * sizeof(float), stream);
  hipLaunchKernelGGL(k_prep_lm, dim3(1250), dim3(256), 0, stream,
                     lm_X, lm_Y, Wk, ws + OFF_K, ws + OFF_F);
  hipLaunchKernelGGL(k_prep_tg, dim3(625), dim3(256), 0, stream,
                     tg_X, Wq, ws + OFF_Q);
  hipLaunchKernelGGL(k_reduce_lm, dim3(80), dim3(256), 0, stream,
                     ws + OFF_F, lm_delay, g1, al, be, ws + OFF_RED);
  hipLaunchKernelGGL(k_attn, dim3(625), dim3(256), 0, stream,
                     ws + OFF_K, ws + OFF_F, ws + OFF_Q,
                     ws + OFF_ASUM, ws + OFF_AGG);
  hipLaunchKernelGGL(k_router, dim3(1), dim3(32), 0, stream,
                     ws + OFF_RED, ws + OFF_R01, W1, b1);
  hipLaunchKernelGGL(k_final, dim3(625), dim3(256), 0, stream,
                     tg_X, tg_delay, ws + OFF_ASUM, ws + OFF_AGG, ws + OFF_R01,
                     W1, b1, W2, b2, Wg, bg, Wa, ba, g2, g3, al, be, out);
}

// Round 2
// 485.566 us; speedup vs baseline: 2.6103x; 2.6103x over previous
//
#include <hip/hip_runtime.h>
#include <math.h>

#define N1 10000
#define N2 5000
#define DIN 30
#define DZ 32
#define JC 2
#define CHUNK 5000   // N1/JC
#define TJ 128       // j subtile
#define NSUB 40      // ceil(CHUNK/TJ)

// workspace layout (float offsets)
#define OFF_K    0        // K_proj [N1][32]
#define OFF_F    320000   // lm_feature padded [N1][32]
#define OFF_Q    640000   // Q_proj [N2][32]
#define OFF_Z    800000   // softmax denom Z [N2]
#define OFF_ASUM 805000   // asum [N2]
#define OFF_AGG  810000   // aggvec [N2][32]
#define OFF_RED  970000   // rsum[32], dvec[32], ds_sum[1]
#define OFF_R01  970072   // router_0[32], router_1[32]

__device__ __forceinline__ float softplus_f(float x) {
  return fmaxf(x, 0.f) + log1pf(__expf(-fabsf(x)));
}

// K_proj[j][z] = dot(lm_X[j], Wk[z]); F[j][z] = lm_feature (row-major in ws)
__global__ __launch_bounds__(256) void k_prep_lm(const float* __restrict__ lm_X,
    const float* __restrict__ lm_Y, const float* __restrict__ Wk,
    float* __restrict__ Kp, float* __restrict__ Fp) {
  int idx = blockIdx.x * 256 + threadIdx.x;
  if (idx >= N1 * DZ) return;
  int j = idx >> 5, z = idx & 31;
  const float* xr = lm_X + j * DIN;
  const float* wr = Wk + z * DIN;
  float s = 0.f;
#pragma unroll
  for (int k = 0; k < DIN; ++k) s += xr[k] * wr[k];
  Kp[idx] = s;
  Fp[idx] = (z < DIN) ? xr[z] : lm_Y[j * 2 + (z - DIN)];
}

__global__ __launch_bounds__(256) void k_prep_tg(const float* __restrict__ tg_X,
    const float* __restrict__ Wq, float* __restrict__ Qp) {
  int idx = blockIdx.x * 256 + threadIdx.x;
  if (idx >= N2 * DZ) return;
  int i = idx >> 5, z = idx & 31;
  const float* xr = tg_X + i * DIN;
  const float* wr = Wq + z * DIN;
  float s = 0.f;
#pragma unroll
  for (int k = 0; k < DIN; ++k) s += xr[k] * wr[k];
  Qp[idx] = s;
}

// reductions over landmarks: rsum[32], dvec[32] (delay_score @ F), ds_sum
__global__ __launch_bounds__(256) void k_reduce_lm(const float* __restrict__ Fp,
    const float* __restrict__ lm_delay, const float* __restrict__ g1p,
    const float* __restrict__ ap, const float* __restrict__ bp,
    float* __restrict__ red) {
  const int z = threadIdx.x & 31, jg = threadIdx.x >> 5;
  const float a = ap[0], b = bp[0], g1 = g1p[0];
  float rs = 0.f, dv = 0.f, dss = 0.f;
  for (int j = blockIdx.x * 8 + jg; j < N1; j += 80 * 8) {
    float f = Fp[j * DZ + z];
    float ds = __expf(-g1 * (a * lm_delay[j] + b));
    rs += f; dv += ds * f;
    if (z == 0) dss += ds;
  }
  __shared__ float sb0[8][32], sb1[8][32], sd[8];
  sb0[jg][z] = rs; sb1[jg][z] = dv;
  if (z == 0) sd[jg] = dss;
  __syncthreads();
  if (threadIdx.x < 32) {
    float t0 = 0.f, t1 = 0.f;
#pragma unroll
    for (int g = 0; g < 8; ++g) { t0 += sb0[g][threadIdx.x]; t1 += sb1[g][threadIdx.x]; }
    atomicAdd(&red[threadIdx.x], t0);
    atomicAdd(&red[32 + threadIdx.x], t1);
  } else if (threadIdx.x == 32) {
    float t = 0.f;
#pragma unroll
    for (int g = 0; g < 8; ++g) t += sd[g];
    atomicAdd(&red[64], t);
  }
}

// ---- pass A: Z[i] = sum_j exp(s_ij) over this block's j-chunk (atomic) ----
// LDS tile is chunk-major: 16B unit (m, j) at [m*TJ + j] -> conflict-free reads.
__global__ __launch_bounds__(256) void k_attnA(const float4* __restrict__ Kp4,
    const float* __restrict__ Qp, float* __restrict__ Z) {
  __shared__ float4 sK[2][TJ * 8];
  const int tid = threadIdx.x, lane = tid & 63, wid = tid >> 6;
  const int c = blockIdx.x & (JC - 1), itile = blockIdx.x >> 1;
  const int i0 = itile * 8 + wid * 2, i1 = i0 + 1;
  const float rt = 0.17677669529663687f;  // 1/sqrt(32)
  float4 q0[8], q1[8];
  const float4* Q0 = (const float4*)(Qp + i0 * DZ);
  const float4* Q1 = (const float4*)(Qp + i1 * DZ);
#pragma unroll
  for (int m = 0; m < 8; ++m) { q0[m] = Q0[m]; q1[m] = Q1[m]; }
  const int C0 = c * CHUNK * 8;

  auto stage = [&](int sub, int b) {
    const int base = C0 + sub * TJ * 8;
#pragma unroll
    for (int r = 0; r < 4; ++r) {
      int u = r * 256 + tid;                     // linear LDS 16B unit
      int gi = base + (u & (TJ - 1)) * 8 + (u >> 7);  // permuted global gather
      gi = min(gi, N1 * 8 - 1);
      sK[b][u] = Kp4[gi];
    }
  };
  stage(0, 0);
  __syncthreads();
  float zs0 = 0.f, zs1 = 0.f;
  for (int sub = 0; sub < NSUB; ++sub) {
    const int b = sub & 1;
    if (sub + 1 < NSUB) stage(sub + 1, b ^ 1);
    const int jcnt = min(TJ, CHUNK - sub * TJ);
#pragma unroll
    for (int it = 0; it < 2; ++it) {
      const int jj = it * 64 + lane;
      float s0 = 0.f, s1 = 0.f;
#pragma unroll
      for (int m = 0; m < 8; ++m) {
        float4 kv = sK[b][m * TJ + jj];
        s0 += q0[m].x * kv.x + q0[m].y * kv.y + q0[m].z * kv.z + q0[m].w * kv.w;
        s1 += q1[m].x * kv.x + q1[m].y * kv.y + q1[m].z * kv.z + q1[m].w * kv.w;
      }
      if (jj < jcnt) {
        zs0 += __expf(s0 * rt);
        zs1 += __expf(s1 * rt);
      }
    }
    __syncthreads();
  }
#pragma unroll
  for (int m = 1; m < 64; m <<= 1) {
    zs0 += __shfl_xor(zs0, m, 64);
    zs1 += __shfl_xor(zs1, m, 64);
  }
  if (lane == 0) { atomicAdd(&Z[i0], zs0); atomicAdd(&Z[i1], zs1); }
}

// ---- pass B: t = exp(exp(s)/Z); asum += t; aggvec += t*F (atomic) ----
__global__ __launch_bounds__(256) void k_attnB(const float4* __restrict__ Kp4,
    const float4* __restrict__ Fp4, const float* __restrict__ Qp,
    const float* __restrict__ Z, float* __restrict__ asum,
    float* __restrict__ aggvec) {
  __shared__ float4 sK[2][TJ * 8];
  __shared__ float4 sF[2][TJ * 8];
  const int tid = threadIdx.x, lane = tid & 63, wid = tid >> 6;
  const int c = blockIdx.x & (JC - 1), itile = blockIdx.x >> 1;
  const int i0 = itile * 8 + wid * 2, i1 = i0 + 1;
  const float rt = 0.17677669529663687f;
  float4 q0[8], q1[8];
  const float4* Q0 = (const float4*)(Qp + i0 * DZ);
  const float4* Q1 = (const float4*)(Qp + i1 * DZ);
#pragma unroll
  for (int m = 0; m < 8; ++m) { q0[m] = Q0[m]; q1[m] = Q1[m]; }
  const float invZ0 = 1.f / Z[i0], invZ1 = 1.f / Z[i1];
  const int C0 = c * CHUNK * 8;

  auto stage = [&](int sub, int b) {
    const int base = C0 + sub * TJ * 8;
#pragma unroll
    for (int r = 0; r < 4; ++r) {
      int u = r * 256 + tid;
      int gi = base + (u & (TJ - 1)) * 8 + (u >> 7);
      gi = min(gi, N1 * 8 - 1);
      sK[b][u] = Kp4[gi];
      sF[b][u] = Fp4[gi];
    }
  };
  stage(0, 0);
  __syncthreads();
  float as0 = 0.f, as1 = 0.f;
  float acc0[DZ], acc1[DZ];
#pragma unroll
  for (int z = 0; z < DZ; ++z) { acc0[z] = 0.f; acc1[z] = 0.f; }
  for (int sub = 0; sub < NSUB; ++sub) {
    const int b = sub & 1;
    if (sub + 1 < NSUB) stage(sub + 1, b ^ 1);
    const int jcnt = min(TJ, CHUNK - sub * TJ);
#pragma unroll
    for (int it = 0; it < 2; ++it) {
      const int jj = it * 64 + lane;
      float s0 = 0.f, s1 = 0.f;
#pragma unroll
      for (int m = 0; m < 8; ++m) {
        float4 kv = sK[b][m * TJ + jj];
        s0 += q0[m].x * kv.x + q0[m].y * kv.y + q0[m].z * kv.z + q0[m].w * kv.w;
        s1 += q1[m].x * kv.x + q1[m].y * kv.y + q1[m].z * kv.z + q1[m].w * kv.w;
      }
      float t0 = __expf(__expf(s0 * rt) * invZ0);
      float t1 = __expf(__expf(s1 * rt) * invZ1);
      if (jj >= jcnt) { t0 = 0.f; t1 = 0.f; }
      as0 += t0; as1 += t1;
#pragma unroll
      for (int m = 0; m < 8; ++m) {
        float4 fv = sF[b][m * TJ + jj];
        acc0[4 * m + 0] += t0 * fv.x; acc0[4 * m + 1] += t0 * fv.y;
        acc0[4 * m + 2] += t0 * fv.z; acc0[4 * m + 3] += t0 * fv.w;
        acc1[4 * m + 0] += t1 * fv.x; acc1[4 * m + 1] += t1 * fv.y;
        acc1[4 * m + 2] += t1 * fv.z; acc1[4 * m + 3] += t1 * fv.w;
      }
    }
    __syncthreads();
  }
#pragma unroll
  for (int m = 1; m < 64; m <<= 1) {
    as0 += __shfl_xor(as0, m, 64);
    as1 += __shfl_xor(as1, m, 64);
  }
  if (lane == 0) { atomicAdd(&asum[i0], as0); atomicAdd(&asum[i1], as1); }
#pragma unroll
  for (int z = 0; z < DZ; ++z) {
    float r0 = acc0[z], r1 = acc1[z];
#pragma unroll
    for (int m = 1; m < 64; m <<= 1) {
      r0 += __shfl_xor(r0, m, 64);
      r1 += __shfl_xor(r1, m, 64);
    }
    if (lane == z) {
      atomicAdd(&aggvec[i0 * DZ + z], r0);
      atomicAdd(&aggvec[i1 * DZ + z], r1);
    }
  }
}

// router_0 and router_1 (tiny)
__global__ void k_router(const float* __restrict__ red, float* __restrict__ r01,
    const float* __restrict__ W1, const float* __restrict__ b1) {
  __shared__ float s_aggr[DZ];
  const int z = threadIdx.x;
  const float r0 = red[z] / (float)N1;
  const float deg_r = 1.f + red[64] + 1e-12f;
  s_aggr[z] = (r0 + red[32 + z]) / deg_r;
  r01[z] = r0;
  __syncthreads();
  float acc = b1[z];
#pragma unroll
  for (int k = 0; k < DZ; ++k) acc += W1[z * DZ + k] * s_aggr[k];
  r01[DZ + z] = acc;
}

// per-target tail: two 32x32 matvecs + heads
__global__ __launch_bounds__(256) void k_final(
    const float* __restrict__ tg_X, const float* __restrict__ tg_delay,
    const float* __restrict__ asum, const float* __restrict__ aggvec,
    const float* __restrict__ r01,
    const float* __restrict__ W1, const float* __restrict__ b1,
    const float* __restrict__ W2, const float* __restrict__ b2,
    const float* __restrict__ Wg, const float* __restrict__ bg,
    const float* __restrict__ Wa, const float* __restrict__ ba,
    const float* __restrict__ g2p, const float* __restrict__ g3p,
    const float* __restrict__ ap, const float* __restrict__ bp,
    float* __restrict__ out) {
  __shared__ float s_a[8][DZ], s_t1[8][DZ], s_t2[8][DZ];
  const int z = threadIdx.x & 31, li = threadIdx.x >> 5;
  const int i = blockIdx.x * 8 + li;
  const float a = ap[0], b = bp[0], g2 = g2p[0], g3 = g3p[0];
  const float td = tg_delay[i];
  const float rt0 = __expf(-g2 * (a * td + b));
  const float rt1 = __expf(-g3 * (a * td + b));
  const float tgx = (z < DIN) ? tg_X[i * DIN + z] : 0.f;
  const float deg = 1.f + asum[i] + rt0 + 1e-12f;
  s_a[li][z] = (tgx + aggvec[i * DZ + z] + rt0 * r01[z]) / deg;
  __syncthreads();
  float t1 = b1[z];
#pragma unroll
  for (int k = 0; k < DZ; ++k) t1 += W1[z * DZ + k] * s_a[li][k];
  s_t1[li][z] = t1;
  __syncthreads();
  s_a[li][z] = (t1 + rt1 * r01[DZ + z]) / (1.f + rt1 + 1e-12f);
  __syncthreads();
  float t2 = b2[z];
#pragma unroll
  for (int k = 0; k < DZ; ++k) t2 += W2[z * DZ + k] * s_a[li][k];
  s_t2[li][z] = t2;
  __syncthreads();
  if (z < 5) {
    float og = bg[z];
#pragma unroll
    for (int k = 0; k < DZ; ++k) og += Wg[z * 64 + k] * s_t1[li][k];
#pragma unroll
    for (int k = 0; k < DZ; ++k) og += Wg[z * 64 + DZ + k] * s_t2[li][k];
    if (z == 0)      out[2 * i] = og;
    else if (z == 1) out[2 * i + 1] = og;
    else if (z == 2) out[10000 + i] = softplus_f(og);
    else if (z == 3) out[15000 + i] = softplus_f(og) + 1.f;
    else             out[20000 + i] = softplus_f(og);
  } else if (z >= 8 && z < 13) {
    const int h = z - 8;
    float oa = ba[h];
#pragma unroll
    for (int k = 0; k < DIN; ++k) oa += Wa[h * DIN + k] * tg_X[i * DIN + k];
    if (h == 0)      out[25000 + 2 * i] = oa;
    else if (h == 1) out[25000 + 2 * i + 1] = oa;
    else if (h == 2) out[35000 + i] = softplus_f(oa);
    else if (h == 3) out[40000 + i] = softplus_f(oa) + 1.f;
    else             out[45000 + i] = softplus_f(oa);
  }
}

extern "C" void kernel_launch(void* const* d_in, const int* in_sizes, int n_in,
                              void* d_out, int out_size, void* d_ws, size_t ws_size,
                              hipStream_t stream) {
  const float* lm_X    = (const float*)d_in[0];
  const float* lm_Y    = (const float*)d_in[1];
  const float* tg_X    = (const float*)d_in[2];
  const float* lm_delay= (const float*)d_in[4];
  const float* tg_delay= (const float*)d_in[5];
  const float* Wq      = (const float*)d_in[6];
  const float* Wk      = (const float*)d_in[7];
  const float* g1      = (const float*)d_in[9];
  const float* g2      = (const float*)d_in[10];
  const float* g3      = (const float*)d_in[11];
  const float* al      = (const float*)d_in[12];
  const float* be      = (const float*)d_in[13];
  const float* W1      = (const float*)d_in[14];
  const float* b1      = (const float*)d_in[15];
  const float* W2      = (const float*)d_in[16];
  const float* b2      = (const float*)d_in[17];
  const float* Wg      = (const float*)d_in[18];
  const float* bg      = (const float*)d_in[19];
  const float* Wa      = (const float*)d_in[20];
  const float* ba      = (const float*)d_in[21];
  float* out = (float*)d_out;
  float* ws  = (float*)d_ws;

  // zero all accumulators (Z, asum, aggvec, red) in one contiguous memset
  hipMemsetAsync(ws + OFF_Z, 0, (OFF_RED + 65 - OFF_Z) * sizeof(float), stream);
  hipLaunchKernelGGL(k_prep_lm, dim3(1250), dim3(256), 0, stream,
                     lm_X, lm_Y, Wk, ws + OFF_K, ws + OFF_F);
  hipLaunchKernelGGL(k_prep_tg, dim3(625), dim3(256), 0, stream,
                     tg_X, Wq, ws + OFF_Q);
  hipLaunchKernelGGL(k_reduce_lm, dim3(80), dim3(256), 0, stream,
                     ws + OFF_F, lm_delay, g1, al, be, ws + OFF_RED);
  hipLaunchKernelGGL(k_attnA, dim3(625 * JC), dim3(256), 0, stream,
                     (const float4*)(ws + OFF_K), ws + OFF_Q, ws + OFF_Z);
  hipLaunchKernelGGL(k_attnB, dim3(625 * JC), dim3(256), 0, stream,
                     (const float4*)(ws + OFF_K), (const float4*)(ws + OFF_F),
                     ws + OFF_Q, ws + OFF_Z, ws + OFF_ASUM, ws + OFF_AGG);
  hipLaunchKernelGGL(k_router, dim3(1), dim3(32), 0, stream,
                     ws + OFF_RED, ws + OFF_R01, W1, b1);
  hipLaunchKernelGGL(k_final, dim3(625), dim3(256), 0, stream,
                     tg_X, tg_delay, ws + OFF_ASUM, ws + OFF_AGG, ws + OFF_R01,
                     W1, b1, W2, b2, Wg, bg, Wa, ba, g2, g3, al, be, out);
}

// Round 3
// 129.069 us; speedup vs baseline: 9.8202x; 3.7621x over previous
//
#include <hip/hip_runtime.h>
#include <math.h>

#define N1 10000
#define N2 5000
#define DIN 30
#define DZ 32
#define N1P 10016   // padded to 313*32
#define N2P 5024    // padded to 157*32
#define NTJ 313     // j-tiles of 32
#define NTI 157     // i-tiles of 32
#define NCH 4       // j-chunks (78,78,78,79 tiles)

// byte offsets in ws
#define OFFB_K    0u        // bf16 K[N1P][32]
#define OFFB_FZ   641024u   // bf16 Fz[32][N1P]   (z-major features)
#define OFFB_Q    1282048u  // bf16 Q[N2P][32]
#define OFFB_ZP   1603584u  // f32 Z_part[4][N2P]
#define OFFB_AS   1683968u  // f32 asum_part[4][N2P]
#define OFFB_AGP  1764352u  // bf16 agg_part[4][N2P][32]
#define OFFB_RED  3050496u  // f32 red[65]: rsum[32], dvec[32], ds_sum
#define OFFB_R01  3050756u  // f32 r01[64]: router_0[32], router_1[32]

typedef __bf16 bf16x8 __attribute__((ext_vector_type(8)));
typedef float f32x16 __attribute__((ext_vector_type(16)));

union W4 { unsigned w[4]; bf16x8 v; };

__device__ __forceinline__ float softplus_f(float x) {
  return fmaxf(x, 0.f) + log1pf(__expf(-fabsf(x)));
}
__device__ __forceinline__ unsigned pack2bf(float a, float b) {
  union { __bf16 h[2]; unsigned u; } x;
  x.h[0] = (__bf16)a; x.h[1] = (__bf16)b; return x.u;
}

// K_bf16[j][z] = dot(lm_X[j], Wk[z]); Fz_bf16[z][j] = lm_feature transposed.
// Grid 157 blocks x 256 thr; block handles 64 j-rows. Pads (j>=N1) -> 0.
__global__ __launch_bounds__(256) void k_prep_lm(const float* __restrict__ lm_X,
    const float* __restrict__ lm_Y, const float* __restrict__ Wk,
    __bf16* __restrict__ Kb, __bf16* __restrict__ Fzb) {
  __shared__ __bf16 sF[64][33];
  const int j0 = blockIdx.x * 64;
  const int z = threadIdx.x & 31, jl = threadIdx.x >> 5;
  for (int jj = jl; jj < 64; jj += 8) {
    const int j = j0 + jj;
    float s = 0.f, fval = 0.f;
    if (j < N1) {
      const float* xr = lm_X + j * DIN;
      const float* wr = Wk + z * DIN;
#pragma unroll
      for (int k = 0; k < DIN; ++k) s += xr[k] * wr[k];
      fval = (z < DIN) ? xr[z] : lm_Y[j * 2 + (z - DIN)];
    }
    if (j < N1P) Kb[j * DZ + z] = (__bf16)s;
    sF[jj][z] = (__bf16)fval;
  }
  __syncthreads();
  const int z2 = threadIdx.x >> 3, sub = threadIdx.x & 7;
  const int jbase = j0 + sub * 8;
  if (jbase < N1P) {
    bf16x8 v;
#pragma unroll
    for (int e = 0; e < 8; ++e) v[e] = sF[sub * 8 + e][z2];
    *(bf16x8*)(Fzb + (size_t)z2 * N1P + jbase) = v;
  }
}

// Q_bf16[i][z] = dot(tg_X[i], Wq[z]); pads (i>=N2) -> 0. Grid 628 x 256.
__global__ __launch_bounds__(256) void k_prep_tg(const float* __restrict__ tg_X,
    const float* __restrict__ Wq, __bf16* __restrict__ Qb) {
  const int idx = blockIdx.x * 256 + threadIdx.x;  // < N2P*32 = 160768
  const int i = idx >> 5, z = idx & 31;
  float s = 0.f;
  if (i < N2) {
    const float* xr = tg_X + i * DIN;
    const float* wr = Wq + z * DIN;
#pragma unroll
    for (int k = 0; k < DIN; ++k) s += xr[k] * wr[k];
  }
  Qb[idx] = (__bf16)s;
}

// rsum[32] (col-sum of features, f32 exact), dvec[32] (delay_score @ F), ds_sum
__global__ __launch_bounds__(256) void k_reduce_lm(const float* __restrict__ lm_X,
    const float* __restrict__ lm_Y, const float* __restrict__ lm_delay,
    const float* __restrict__ g1p, const float* __restrict__ ap,
    const float* __restrict__ bp, float* __restrict__ red) {
  const int z = threadIdx.x & 31, jg = threadIdx.x >> 5;
  const float a = ap[0], b = bp[0], g1 = g1p[0];
  float rs = 0.f, dv = 0.f, dss = 0.f;
  for (int j = blockIdx.x * 8 + jg; j < N1; j += 80 * 8) {
    float f = (z < DIN) ? lm_X[j * DIN + z] : lm_Y[j * 2 + (z - DIN)];
    float ds = __expf(-g1 * (a * lm_delay[j] + b));
    rs += f; dv += ds * f;
    if (z == 0) dss += ds;
  }
  __shared__ float sb0[8][32], sb1[8][32], sd[8];
  sb0[jg][z] = rs; sb1[jg][z] = dv;
  if (z == 0) sd[jg] = dss;
  __syncthreads();
  if (threadIdx.x < 32) {
    float t0 = 0.f, t1 = 0.f;
#pragma unroll
    for (int g = 0; g < 8; ++g) { t0 += sb0[g][threadIdx.x]; t1 += sb1[g][threadIdx.x]; }
    atomicAdd(&red[threadIdx.x], t0);
    atomicAdd(&red[32 + threadIdx.x], t1);
  } else if (threadIdx.x == 32) {
    float t = 0.f;
#pragma unroll
    for (int g = 0; g < 8; ++g) t += sd[g];
    atomicAdd(&red[64], t);
  }
}

// pass A: Z_part[c][i] = sum_{j in chunk} exp(s_ij/temp).  S^T = K·Q^T via MFMA.
// D layout: col=lane&31 -> i, row=(r&3)+8*(r>>2)+4*hi -> j_local.
__global__ __launch_bounds__(64) void k_attnA(const __bf16* __restrict__ Kb,
    const __bf16* __restrict__ Qb, float* __restrict__ Zp) {
  const int unit = blockIdx.x;
  const int it = unit >> 2, c = unit & 3;
  const int i0 = it * 32;
  const int lane = threadIdx.x, li = lane & 31, hi = lane >> 5;
  const float rt = 0.17677669529663687f;  // 1/sqrt(32)
  const bf16x8 b0 = *(const bf16x8*)(Qb + (i0 + li) * DZ + hi * 8);
  const bf16x8 b1 = *(const bf16x8*)(Qb + (i0 + li) * DZ + 16 + hi * 8);
  float z = 0.f;
  const int t0 = c * 78, t1 = (c == NCH - 1) ? NTJ : t0 + 78;
  for (int t = t0; t < t1; ++t) {
    const int jt = t * 32;
    bf16x8 a0 = *(const bf16x8*)(Kb + (jt + li) * DZ + hi * 8);
    bf16x8 a1 = *(const bf16x8*)(Kb + (jt + li) * DZ + 16 + hi * 8);
    f32x16 acc = {0.f,0.f,0.f,0.f,0.f,0.f,0.f,0.f,0.f,0.f,0.f,0.f,0.f,0.f,0.f,0.f};
    acc = __builtin_amdgcn_mfma_f32_32x32x16_bf16(a0, b0, acc, 0, 0, 0);
    acc = __builtin_amdgcn_mfma_f32_32x32x16_bf16(a1, b1, acc, 0, 0, 0);
    if (t != NTJ - 1) {
#pragma unroll
      for (int r = 0; r < 16; ++r) z += __expf(acc[r] * rt);
    } else {  // pad j-rows are exactly regs 8..15 of the last tile
#pragma unroll
      for (int r = 0; r < 8; ++r) z += __expf(acc[r] * rt);
    }
  }
  z += __shfl_xor(z, 32, 64);
  if (hi == 0) Zp[c * N2P + i0 + li] = z;
}

// pass B: P' = expm1(exp(s/temp)/Z) ~ attn + attn^2/2; asum_part = sum P';
// agg_part = P'·F via MFMA (A-frag built by pack + shfl_xor(32) + select).
__global__ __launch_bounds__(64) void k_attnB(const __bf16* __restrict__ Kb,
    const __bf16* __restrict__ Fzb, const __bf16* __restrict__ Qb,
    const float* __restrict__ Zp, float* __restrict__ asum_p,
    __bf16* __restrict__ agg_p) {
  const int unit = blockIdx.x;
  const int it = unit >> 2, c = unit & 3;
  const int i0 = it * 32;
  const int lane = threadIdx.x, li = lane & 31, hi = lane >> 5;
  const float rt = 0.17677669529663687f;
  const bf16x8 b0 = *(const bf16x8*)(Qb + (i0 + li) * DZ + hi * 8);
  const bf16x8 b1 = *(const bf16x8*)(Qb + (i0 + li) * DZ + 16 + hi * 8);
  const int i = i0 + li;
  const float Zt = Zp[i] + Zp[N2P + i] + Zp[2 * N2P + i] + Zp[3 * N2P + i];
  const float invZ = 1.f / Zt;
  float asl = 0.f;
  f32x16 pacc = {0.f,0.f,0.f,0.f,0.f,0.f,0.f,0.f,0.f,0.f,0.f,0.f,0.f,0.f,0.f,0.f};
  const int t0 = c * 78, t1 = (c == NCH - 1) ? NTJ : t0 + 78;
  const bool h = (hi != 0);
  for (int t = t0; t < t1; ++t) {
    const int jt = t * 32;
    bf16x8 a0 = *(const bf16x8*)(Kb + (jt + li) * DZ + hi * 8);
    bf16x8 a1 = *(const bf16x8*)(Kb + (jt + li) * DZ + 16 + hi * 8);
    bf16x8 fb0 = *(const bf16x8*)(Fzb + (size_t)li * N1P + jt + hi * 8);
    bf16x8 fb1 = *(const bf16x8*)(Fzb + (size_t)li * N1P + jt + 16 + hi * 8);
    f32x16 sacc = {0.f,0.f,0.f,0.f,0.f,0.f,0.f,0.f,0.f,0.f,0.f,0.f,0.f,0.f,0.f,0.f};
    sacc = __builtin_amdgcn_mfma_f32_32x32x16_bf16(a0, b0, sacc, 0, 0, 0);
    sacc = __builtin_amdgcn_mfma_f32_32x32x16_bf16(a1, b1, sacc, 0, 0, 0);
    float p[16];
#pragma unroll
    for (int r = 0; r < 16; ++r) {
      float at = __expf(sacc[r] * rt) * invZ;
      p[r] = at + 0.5f * at * at;   // expm1(at), 2nd order (at ~ 1e-4)
    }
    if (t == NTJ - 1) {
#pragma unroll
      for (int r = 8; r < 16; ++r) p[r] = 0.f;   // mask pad j-rows
    }
#pragma unroll
    for (int r = 0; r < 16; ++r) asl += p[r];
    unsigned u[8], pu[8];
#pragma unroll
    for (int k2 = 0; k2 < 8; ++k2) {
      u[k2] = pack2bf(p[2 * k2], p[2 * k2 + 1]);
      pu[k2] = __shfl_xor(u[k2], 32, 64);
    }
    W4 A1, A2;
    A1.w[0] = h ? pu[2] : u[0];
    A1.w[1] = h ? pu[3] : u[1];
    A1.w[2] = h ? u[2]  : pu[0];
    A1.w[3] = h ? u[3]  : pu[1];
    A2.w[0] = h ? pu[6] : u[4];
    A2.w[1] = h ? pu[7] : u[5];
    A2.w[2] = h ? u[6]  : pu[4];
    A2.w[3] = h ? u[7]  : pu[5];
    pacc = __builtin_amdgcn_mfma_f32_32x32x16_bf16(A1.v, fb0, pacc, 0, 0, 0);
    pacc = __builtin_amdgcn_mfma_f32_32x32x16_bf16(A2.v, fb1, pacc, 0, 0, 0);
  }
  asl += __shfl_xor(asl, 32, 64);
  if (hi == 0) asum_p[c * N2P + i0 + li] = asl;
  // pacc: D[irow][z=li], irow=(r&3)+8*(r>>2)+4*hi
#pragma unroll
  for (int r = 0; r < 16; ++r) {
    const int irow = (r & 3) + 8 * (r >> 2) + 4 * hi;
    agg_p[((size_t)c * N2P + i0 + irow) * DZ + li] = (__bf16)pacc[r];
  }
}

// router_0 and router_1 (tiny)
__global__ void k_router(const float* __restrict__ red, float* __restrict__ r01,
    const float* __restrict__ W1, const float* __restrict__ b1) {
  __shared__ float s_aggr[DZ];
  const int z = threadIdx.x;
  const float r0 = red[z] / (float)N1;
  const float deg_r = 1.f + red[64] + 1e-12f;
  s_aggr[z] = (r0 + red[32 + z]) / deg_r;
  r01[z] = r0;
  __syncthreads();
  float acc = b1[z];
#pragma unroll
  for (int k = 0; k < DZ; ++k) acc += W1[z * DZ + k] * s_aggr[k];
  r01[DZ + z] = acc;
}

// per-target tail: reduce partials, two 32x32 matvecs + heads
__global__ __launch_bounds__(256) void k_final(
    const float* __restrict__ tg_X, const float* __restrict__ tg_delay,
    const float* __restrict__ asum_p, const __bf16* __restrict__ agg_p,
    const float* __restrict__ red, const float* __restrict__ r01,
    const float* __restrict__ W1, const float* __restrict__ b1,
    const float* __restrict__ W2, const float* __restrict__ b2,
    const float* __restrict__ Wg, const float* __restrict__ bg,
    const float* __restrict__ Wa, const float* __restrict__ ba,
    const float* __restrict__ g2p, const float* __restrict__ g3p,
    const float* __restrict__ ap, const float* __restrict__ bp,
    float* __restrict__ out) {
  __shared__ float s_a[8][DZ], s_t1[8][DZ], s_t2[8][DZ];
  const int z = threadIdx.x & 31, li = threadIdx.x >> 5;
  const int i = blockIdx.x * 8 + li;
  const float a = ap[0], b = bp[0], g2 = g2p[0], g3 = g3p[0];
  const float td = tg_delay[i];
  const float rt0 = __expf(-g2 * (a * td + b));
  const float rt1 = __expf(-g3 * (a * td + b));
  const float tgx = (z < DIN) ? tg_X[i * DIN + z] : 0.f;
  float aggsum = red[z];  // rsum (the "1.0 * F" part of t = 1 + P')
  float asum_t = 0.f;
#pragma unroll
  for (int cc = 0; cc < NCH; ++cc) {
    aggsum += (float)agg_p[((size_t)cc * N2P + i) * DZ + z];
    if (z == 0) asum_t += asum_p[cc * N2P + i];
  }
  __shared__ float s_as[8];
  if (z == 0) s_as[li] = asum_t;
  __syncthreads();
  const float sum_t = 10000.f + s_as[li];  // sum of attribute_score
  const float deg = 1.f + sum_t + rt0 + 1e-12f;
  s_a[li][z] = (tgx + aggsum + rt0 * r01[z]) / deg;
  __syncthreads();
  float t1 = b1[z];
#pragma unroll
  for (int k = 0; k < DZ; ++k) t1 += W1[z * DZ + k] * s_a[li][k];
  s_t1[li][z] = t1;
  __syncthreads();
  s_a[li][z] = (t1 + rt1 * r01[DZ + z]) / (1.f + rt1 + 1e-12f);
  __syncthreads();
  float t2 = b2[z];
#pragma unroll
  for (int k = 0; k < DZ; ++k) t2 += W2[z * DZ + k] * s_a[li][k];
  s_t2[li][z] = t2;
  __syncthreads();
  if (z < 5) {
    float og = bg[z];
#pragma unroll
    for (int k = 0; k < DZ; ++k) og += Wg[z * 64 + k] * s_t1[li][k];
#pragma unroll
    for (int k = 0; k < DZ; ++k) og += Wg[z * 64 + DZ + k] * s_t2[li][k];
    if (z == 0)      out[2 * i] = og;
    else if (z == 1) out[2 * i + 1] = og;
    else if (z == 2) out[10000 + i] = softplus_f(og);
    else if (z == 3) out[15000 + i] = softplus_f(og) + 1.f;
    else             out[20000 + i] = softplus_f(og);
  } else if (z >= 8 && z < 13) {
    const int hh = z - 8;
    float oa = ba[hh];
#pragma unroll
    for (int k = 0; k < DIN; ++k) oa += Wa[hh * DIN + k] * tg_X[i * DIN + k];
    if (hh == 0)      out[25000 + 2 * i] = oa;
    else if (hh == 1) out[25000 + 2 * i + 1] = oa;
    else if (hh == 2) out[35000 + i] = softplus_f(oa);
    else if (hh == 3) out[40000 + i] = softplus_f(oa) + 1.f;
    else              out[45000 + i] = softplus_f(oa);
  }
}

extern "C" void kernel_launch(void* const* d_in, const int* in_sizes, int n_in,
                              void* d_out, int out_size, void* d_ws, size_t ws_size,
                              hipStream_t stream) {
  const float* lm_X    = (const float*)d_in[0];
  const float* lm_Y    = (const float*)d_in[1];
  const float* tg_X    = (const float*)d_in[2];
  const float* lm_delay= (const float*)d_in[4];
  const float* tg_delay= (const float*)d_in[5];
  const float* Wq      = (const float*)d_in[6];
  const float* Wk      = (const float*)d_in[7];
  const float* g1      = (const float*)d_in[9];
  const float* g2      = (const float*)d_in[10];
  const float* g3      = (const float*)d_in[11];
  const float* al      = (const float*)d_in[12];
  const float* be      = (const float*)d_in[13];
  const float* W1      = (const float*)d_in[14];
  const float* b1      = (const float*)d_in[15];
  const float* W2      = (const float*)d_in[16];
  const float* b2      = (const float*)d_in[17];
  const float* Wg      = (const float*)d_in[18];
  const float* bg      = (const float*)d_in[19];
  const float* Wa      = (const float*)d_in[20];
  const float* ba      = (const float*)d_in[21];
  float* out = (float*)d_out;
  char* ws   = (char*)d_ws;

  __bf16* Kb   = (__bf16*)(ws + OFFB_K);
  __bf16* Fzb  = (__bf16*)(ws + OFFB_FZ);
  __bf16* Qb   = (__bf16*)(ws + OFFB_Q);
  float*  Zp   = (float*)(ws + OFFB_ZP);
  float*  asp  = (float*)(ws + OFFB_AS);
  __bf16* agp  = (__bf16*)(ws + OFFB_AGP);
  float*  red  = (float*)(ws + OFFB_RED);
  float*  r01  = (float*)(ws + OFFB_R01);

  hipMemsetAsync(red, 0, 65 * sizeof(float), stream);
  hipLaunchKernelGGL(k_prep_lm, dim3(157), dim3(256), 0, stream,
                     lm_X, lm_Y, Wk, Kb, Fzb);
  hipLaunchKernelGGL(k_prep_tg, dim3(628), dim3(256), 0, stream,
                     tg_X, Wq, Qb);
  hipLaunchKernelGGL(k_reduce_lm, dim3(80), dim3(256), 0, stream,
                     lm_X, lm_Y, lm_delay, g1, al, be, red);
  hipLaunchKernelGGL(k_attnA, dim3(NTI * NCH), dim3(64), 0, stream,
                     Kb, Qb, Zp);
  hipLaunchKernelGGL(k_attnB, dim3(NTI * NCH), dim3(64), 0, stream,
                     Kb, Fzb, Qb, Zp, asp, agp);
  hipLaunchKernelGGL(k_router, dim3(1), dim3(32), 0, stream,
                     red, r01, W1, b1);
  hipLaunchKernelGGL(k_final, dim3(625), dim3(256), 0, stream,
                     tg_X, tg_delay, asp, agp, red, r01,
                     W1, b1, W2, b2, Wg, bg, Wa, ba, g2, g3, al, be, out);
}

// Round 4
// 60.499 us; speedup vs baseline: 20.9503x; 2.1334x over previous
//
#include <hip/hip_runtime.h>
#include <math.h>

#define N1 10000
#define N2 5000
#define DIN 30
#define DZ 32
#define N1P 10016   // 313*32
#define N2P 5024    // 157*32
#define NTJ 313     // j-tiles of 32
#define NTI 157     // i-tiles of 32
#define NCHB 8      // partial-buffer count (blocks per i-tile)
#define NCH 32      // total j-chunks = NCHB*4 waves
#define CTILES 10   // tiles per chunk (last chunk: 3)

// byte offsets in ws (all 16B aligned)
#define OFFB_K    0u        // bf16 K[N1P][32]
#define OFFB_FZ   641024u   // bf16 Fz[32][N1P]  (z-major features)
#define OFFB_Q    1282048u  // bf16 Q[N2P][32]
#define OFFB_ZP   1603584u  // f32 Z_part[8][N2P]
#define OFFB_M1   1764352u  // bf16 M1_part[8][N2P][32]
#define OFFB_RED  4336640u  // f32 red[65]: rsum[32], dvec[32], ds_sum

typedef __bf16 bf16x8 __attribute__((ext_vector_type(8)));
typedef float f32x16 __attribute__((ext_vector_type(16)));

union W4 { unsigned w[4]; bf16x8 v; };

__device__ __forceinline__ float softplus_f(float x) {
  return fmaxf(x, 0.f) + log1pf(__expf(-fabsf(x)));
}
__device__ __forceinline__ unsigned pack2bf(float a, float b) {
  union { __bf16 h[2]; unsigned u; } x;
  x.h[0] = (__bf16)a; x.h[1] = (__bf16)b; return x.u;
}

// Fused prep: [0,157) K+Fz, [157,785) Q, [785,865) landmark reductions
__global__ __launch_bounds__(256) void k_prep(const float* __restrict__ lm_X,
    const float* __restrict__ lm_Y, const float* __restrict__ tg_X,
    const float* __restrict__ lm_delay, const float* __restrict__ Wq,
    const float* __restrict__ Wk, const float* __restrict__ g1p,
    const float* __restrict__ ap, const float* __restrict__ bp,
    __bf16* __restrict__ Kb, __bf16* __restrict__ Fzb,
    __bf16* __restrict__ Qb, float* __restrict__ red) {
  const int bid = blockIdx.x;
  if (bid < 157) {
    __shared__ __bf16 sF[64][33];
    const int j0 = bid * 64;
    const int z = threadIdx.x & 31, jl = threadIdx.x >> 5;
    for (int jj = jl; jj < 64; jj += 8) {
      const int j = j0 + jj;
      float s = 0.f, fval = 0.f;
      if (j < N1) {
        const float* xr = lm_X + j * DIN;
        const float* wr = Wk + z * DIN;
#pragma unroll
        for (int k = 0; k < DIN; ++k) s += xr[k] * wr[k];
        fval = (z < DIN) ? xr[z] : lm_Y[j * 2 + (z - DIN)];
      }
      if (j < N1P) Kb[j * DZ + z] = (__bf16)s;
      sF[jj][z] = (__bf16)fval;
    }
    __syncthreads();
    const int z2 = threadIdx.x >> 3, sub = threadIdx.x & 7;
    const int jbase = j0 + sub * 8;
    if (jbase < N1P) {
      bf16x8 v;
#pragma unroll
      for (int e = 0; e < 8; ++e) v[e] = sF[sub * 8 + e][z2];
      *(bf16x8*)(Fzb + (size_t)z2 * N1P + jbase) = v;
    }
  } else if (bid < 785) {
    const int idx = (bid - 157) * 256 + threadIdx.x;  // < N2P*32
    const int i = idx >> 5, z = idx & 31;
    float s = 0.f;
    if (i < N2) {
      const float* xr = tg_X + i * DIN;
      const float* wr = Wq + z * DIN;
#pragma unroll
      for (int k = 0; k < DIN; ++k) s += xr[k] * wr[k];
    }
    Qb[idx] = (__bf16)s;
  } else {
    const int b3 = bid - 785;
    const int z = threadIdx.x & 31, jg = threadIdx.x >> 5;
    const float a = ap[0], b = bp[0], g1 = g1p[0];
    float rs = 0.f, dv = 0.f, dss = 0.f;
    for (int j = b3 * 8 + jg; j < N1; j += 80 * 8) {
      float f = (z < DIN) ? lm_X[j * DIN + z] : lm_Y[j * 2 + (z - DIN)];
      float ds = __expf(-g1 * (a * lm_delay[j] + b));
      rs += f; dv += ds * f;
      if (z == 0) dss += ds;
    }
    __shared__ float sb0[8][32], sb1[8][32], sd[8];
    sb0[jg][z] = rs; sb1[jg][z] = dv;
    if (z == 0) sd[jg] = dss;
    __syncthreads();
    if (threadIdx.x < 32) {
      float t0 = 0.f, t1 = 0.f;
#pragma unroll
      for (int g = 0; g < 8; ++g) { t0 += sb0[g][threadIdx.x]; t1 += sb1[g][threadIdx.x]; }
      atomicAdd(&red[threadIdx.x], t0);
      atomicAdd(&red[32 + threadIdx.x], t1);
    } else if (threadIdx.x == 32) {
      float t = 0.f;
#pragma unroll
      for (int g = 0; g < 8; ++g) t += sd[g];
      atomicAdd(&red[64], t);
    }
  }
}

// Single-pass attention: per (i-tile, chunk-group) block, 4 waves = 4 chunks.
// Per wave: S^T tile = K·Q^T (MFMA), E = exp(s/temp); accumulate
//   S1 = sum E (-> Z partial), M1' = sum (E-1)·F via MFMA.
// LDS-reduce the 4 waves -> one partial per block.
__global__ __launch_bounds__(256) void k_attn(const __bf16* __restrict__ Kb,
    const __bf16* __restrict__ Fzb, const __bf16* __restrict__ Qb,
    float* __restrict__ Zp, __bf16* __restrict__ M1p) {
  __shared__ float sZ[4][32];
  __shared__ float sM[4][32][32];
  const int it = blockIdx.x / NCHB, cb = blockIdx.x % NCHB;
  const int i0 = it * 32;
  const int tid = threadIdx.x, lane = tid & 63, wid = tid >> 6;
  const int li = lane & 31, hi = lane >> 5;
  const int c = cb * 4 + wid;                       // chunk 0..31
  const int t0 = c * CTILES, t1 = min(t0 + CTILES, NTJ);
  const float rt = 0.17677669529663687f;            // 1/sqrt(32)
  const bf16x8 b0 = *(const bf16x8*)(Qb + (i0 + li) * DZ + hi * 8);
  const bf16x8 b1 = *(const bf16x8*)(Qb + (i0 + li) * DZ + 16 + hi * 8);
  const bool h = (hi != 0);
  float s1 = 0.f;
  f32x16 pacc = {0.f,0.f,0.f,0.f,0.f,0.f,0.f,0.f,0.f,0.f,0.f,0.f,0.f,0.f,0.f,0.f};
  for (int t = t0; t < t1; ++t) {
    const int jt = t * 32;
    bf16x8 a0 = *(const bf16x8*)(Kb + (jt + li) * DZ + hi * 8);
    bf16x8 a1 = *(const bf16x8*)(Kb + (jt + li) * DZ + 16 + hi * 8);
    bf16x8 fb0 = *(const bf16x8*)(Fzb + (size_t)li * N1P + jt + hi * 8);
    bf16x8 fb1 = *(const bf16x8*)(Fzb + (size_t)li * N1P + jt + 16 + hi * 8);
    f32x16 sacc = {0.f,0.f,0.f,0.f,0.f,0.f,0.f,0.f,0.f,0.f,0.f,0.f,0.f,0.f,0.f,0.f};
    sacc = __builtin_amdgcn_mfma_f32_32x32x16_bf16(a0, b0, sacc, 0, 0, 0);
    sacc = __builtin_amdgcn_mfma_f32_32x32x16_bf16(a1, b1, sacc, 0, 0, 0);
    float em1[16];
#pragma unroll
    for (int r = 0; r < 16; ++r) {
      float e = __expf(sacc[r] * rt);
      em1[r] = e - 1.f;
      s1 += e;
    }
    if (t == NTJ - 1) {   // pad j-rows (j_local 16..31) are regs 8..15
#pragma unroll
      for (int r = 8; r < 16; ++r) { s1 -= (em1[r] + 1.f); em1[r] = 0.f; }
    }
    unsigned u[8], pu[8];
#pragma unroll
    for (int k2 = 0; k2 < 8; ++k2) {
      u[k2] = pack2bf(em1[2 * k2], em1[2 * k2 + 1]);
      pu[k2] = __shfl_xor(u[k2], 32, 64);
    }
    W4 A1, A2;
    A1.w[0] = h ? pu[2] : u[0];
    A1.w[1] = h ? pu[3] : u[1];
    A1.w[2] = h ? u[2]  : pu[0];
    A1.w[3] = h ? u[3]  : pu[1];
    A2.w[0] = h ? pu[6] : u[4];
    A2.w[1] = h ? pu[7] : u[5];
    A2.w[2] = h ? u[6]  : pu[4];
    A2.w[3] = h ? u[7]  : pu[5];
    pacc = __builtin_amdgcn_mfma_f32_32x32x16_bf16(A1.v, fb0, pacc, 0, 0, 0);
    pacc = __builtin_amdgcn_mfma_f32_32x32x16_bf16(A2.v, fb1, pacc, 0, 0, 0);
  }
  s1 += __shfl_xor(s1, 32, 64);
  if (hi == 0) sZ[wid][li] = s1;
#pragma unroll
  for (int r = 0; r < 16; ++r) {
    const int irow = (r & 3) + 8 * (r >> 2) + 4 * hi;
    sM[wid][irow][li] = pacc[r];
  }
  __syncthreads();
  if (tid < 32)
    Zp[cb * N2P + i0 + tid] = sZ[0][tid] + sZ[1][tid] + sZ[2][tid] + sZ[3][tid];
#pragma unroll
  for (int v = 0; v < 4; ++v) {
    const int idx = v * 256 + tid;
    const int row = idx >> 5, z = idx & 31;
    float m = sM[0][row][z] + sM[1][row][z] + sM[2][row][z] + sM[3][row][z];
    M1p[((size_t)cb * N2P + i0 + row) * DZ + z] = (__bf16)m;
  }
}

// per-target tail: reduce partials, router (inline), two 32x32 matvecs + heads
__global__ __launch_bounds__(256) void k_final(
    const float* __restrict__ tg_X, const float* __restrict__ tg_delay,
    const float* __restrict__ Zp, const __bf16* __restrict__ M1p,
    const float* __restrict__ red,
    const float* __restrict__ W1, const float* __restrict__ b1,
    const float* __restrict__ W2, const float* __restrict__ b2,
    const float* __restrict__ Wg, const float* __restrict__ bg,
    const float* __restrict__ Wa, const float* __restrict__ ba,
    const float* __restrict__ g2p, const float* __restrict__ g3p,
    const float* __restrict__ ap, const float* __restrict__ bp,
    float* __restrict__ out) {
  __shared__ float s_a[8][DZ], s_t1[8][DZ], s_t2[8][DZ];
  __shared__ float s_r0[DZ], s_r1[DZ], s_tmp[DZ];
  const int z = threadIdx.x & 31, li = threadIdx.x >> 5;
  const int i = blockIdx.x * 8 + li;
  // inline router (redundant per block, tiny)
  if (li == 0) {
    const float r0 = red[z] * (1.f / (float)N1);
    const float deg_r = 1.f + red[64] + 1e-12f;
    s_r0[z] = r0;
    s_tmp[z] = (r0 + red[32 + z]) / deg_r;   // agg_r
  }
  __syncthreads();
  if (li == 0) {
    float acc = b1[z];
#pragma unroll
    for (int k = 0; k < DZ; ++k) acc += W1[z * DZ + k] * s_tmp[k];
    s_r1[z] = acc;
  }
  const float a = ap[0], b = bp[0], g2 = g2p[0], g3 = g3p[0];
  const float td = tg_delay[i];
  const float rt0 = __expf(-g2 * (a * td + b));
  const float rt1 = __expf(-g3 * (a * td + b));
  const float tgx = (z < DIN) ? tg_X[i * DIN + z] : 0.f;
  float Zt = 0.f, m1 = 0.f;
#pragma unroll
  for (int cc = 0; cc < NCHB; ++cc) {
    Zt += Zp[cc * N2P + i];
    m1 += (float)M1p[((size_t)cc * N2P + i) * DZ + z];
  }
  const float rsum_z = red[z];
  const float aggsum = rsum_z + (m1 + rsum_z) / Zt;     // sum_j t_j F_j
  const float sum_t = (float)N1 + 1.f;                  // sum_j t_j (+O(1e-4))
  const float deg = 1.f + sum_t + rt0 + 1e-12f;
  __syncthreads();
  s_a[li][z] = (tgx + aggsum + rt0 * s_r0[z]) / deg;
  __syncthreads();
  float t1 = b1[z];
#pragma unroll
  for (int k = 0; k < DZ; ++k) t1 += W1[z * DZ + k] * s_a[li][k];
  s_t1[li][z] = t1;
  __syncthreads();
  s_a[li][z] = (t1 + rt1 * s_r1[z]) / (1.f + rt1 + 1e-12f);
  __syncthreads();
  float t2 = b2[z];
#pragma unroll
  for (int k = 0; k < DZ; ++k) t2 += W2[z * DZ + k] * s_a[li][k];
  s_t2[li][z] = t2;
  __syncthreads();
  if (z < 5) {
    float og = bg[z];
#pragma unroll
    for (int k = 0; k < DZ; ++k) og += Wg[z * 64 + k] * s_t1[li][k];
#pragma unroll
    for (int k = 0; k < DZ; ++k) og += Wg[z * 64 + DZ + k] * s_t2[li][k];
    if (z == 0)      out[2 * i] = og;
    else if (z == 1) out[2 * i + 1] = og;
    else if (z == 2) out[10000 + i] = softplus_f(og);
    else if (z == 3) out[15000 + i] = softplus_f(og) + 1.f;
    else             out[20000 + i] = softplus_f(og);
  } else if (z >= 8 && z < 13) {
    const int hh = z - 8;
    float oa = ba[hh];
#pragma unroll
    for (int k = 0; k < DIN; ++k) oa += Wa[hh * DIN + k] * tg_X[i * DIN + k];
    if (hh == 0)      out[25000 + 2 * i] = oa;
    else if (hh == 1) out[25000 + 2 * i + 1] = oa;
    else if (hh == 2) out[35000 + i] = softplus_f(oa);
    else if (hh == 3) out[40000 + i] = softplus_f(oa) + 1.f;
    else              out[45000 + i] = softplus_f(oa);
  }
}

extern "C" void kernel_launch(void* const* d_in, const int* in_sizes, int n_in,
                              void* d_out, int out_size, void* d_ws, size_t ws_size,
                              hipStream_t stream) {
  const float* lm_X    = (const float*)d_in[0];
  const float* lm_Y    = (const float*)d_in[1];
  const float* tg_X    = (const float*)d_in[2];
  const float* lm_delay= (const float*)d_in[4];
  const float* tg_delay= (const float*)d_in[5];
  const float* Wq      = (const float*)d_in[6];
  const float* Wk      = (const float*)d_in[7];
  const float* g1      = (const float*)d_in[9];
  const float* g2      = (const float*)d_in[10];
  const float* g3      = (const float*)d_in[11];
  const float* al      = (const float*)d_in[12];
  const float* be      = (const float*)d_in[13];
  const float* W1      = (const float*)d_in[14];
  const float* b1      = (const float*)d_in[15];
  const float* W2      = (const float*)d_in[16];
  const float* b2      = (const float*)d_in[17];
  const float* Wg      = (const float*)d_in[18];
  const float* bg      = (const float*)d_in[19];
  const float* Wa      = (const float*)d_in[20];
  const float* ba      = (const float*)d_in[21];
  float* out = (float*)d_out;
  char* ws   = (char*)d_ws;

  __bf16* Kb   = (__bf16*)(ws + OFFB_K);
  __bf16* Fzb  = (__bf16*)(ws + OFFB_FZ);
  __bf16* Qb   = (__bf16*)(ws + OFFB_Q);
  float*  Zp   = (float*)(ws + OFFB_ZP);
  __bf16* M1p  = (__bf16*)(ws + OFFB_M1);
  float*  red  = (float*)(ws + OFFB_RED);

  hipMemsetAsync(red, 0, 65 * sizeof(float), stream);
  hipLaunchKernelGGL(k_prep, dim3(865), dim3(256), 0, stream,
                     lm_X, lm_Y, tg_X, lm_delay, Wq, Wk, g1, al, be,
                     Kb, Fzb, Qb, red);
  hipLaunchKernelGGL(k_attn, dim3(NTI * NCHB), dim3(256), 0, stream,
                     Kb, Fzb, Qb, Zp, M1p);
  hipLaunchKernelGGL(k_final, dim3(625), dim3(256), 0, stream,
                     tg_X, tg_delay, Zp, M1p, red,
                     W1, b1, W2, b2, Wg, bg, Wa, ba, g2, g3, al, be, out);
}

// Round 5
// 54.593 us; speedup vs baseline: 23.2171x; 1.1082x over previous
//
#include <hip/hip_runtime.h>
#include <math.h>

#define N1 10000
#define N2 5000
#define DIN 30
#define DZ 32
#define N1P 10016   // 313*32
#define N2P 5024    // 157*32
#define NTJ 313     // j-tiles of 32
#define NTI 157     // i-tiles of 32
#define NCHB 8      // partial buffers per i-tile (blocks per i-tile)
#define CTILES 10   // j-tiles per wave-chunk (32 chunks; last has 3)
#define NRED 16     // landmark-reduction blocks

// byte offsets in ws (16B aligned)
#define OFFB_K    0u        // bf16 K[N1P][32]
#define OFFB_FZ   641024u   // bf16 Fz[32][N1P]  (z-major features)
#define OFFB_Q    1282048u  // bf16 Qs[N2P][32]  (pre-scaled by 1/sqrt(32))
#define OFFB_ZP   1603584u  // f32 Zpart[8][N2P] (sum of em1)
#define OFFB_M1   1764352u  // bf16 M1part[8][N2P][32]
#define OFFB_RP   4336640u  // f32 red_part[16][66]: rsum[32],dvec[32],ds_sum

typedef __bf16 bf16x8 __attribute__((ext_vector_type(8)));
typedef float f32x16 __attribute__((ext_vector_type(16)));

union W4 { unsigned w[4]; bf16x8 v; };

__device__ __forceinline__ float softplus_f(float x) {
  return fmaxf(x, 0.f) + log1pf(__expf(-fabsf(x)));
}
__device__ __forceinline__ unsigned pack2bf(float a, float b) {
  union { __bf16 h[2]; unsigned u; } x;
  x.h[0] = (__bf16)a; x.h[1] = (__bf16)b; return x.u;
}

// Fused prep. blocks [0,157): K+Fz (64 lm rows each); [157,236): Q (64 tg rows);
// [236,252): landmark reductions -> red_part (no atomics).
__global__ __launch_bounds__(256) void k_prep(const float* __restrict__ lm_X,
    const float* __restrict__ lm_Y, const float* __restrict__ tg_X,
    const float* __restrict__ lm_delay, const float* __restrict__ Wq,
    const float* __restrict__ Wk, const float* __restrict__ g1p,
    const float* __restrict__ ap, const float* __restrict__ bp,
    __bf16* __restrict__ Kb, __bf16* __restrict__ Fzb,
    __bf16* __restrict__ Qb, float* __restrict__ rp) {
  const int bid = blockIdx.x;
  const int tid = threadIdx.x;
  if (bid < 157) {
    __shared__ float sX[64 * DIN];      // 7.5 KB
    __shared__ __bf16 sF[64][33];
    const int j0 = bid * 64;
    for (int idx = tid; idx < 64 * DIN; idx += 256) {
      const int g = j0 * DIN + idx;
      sX[idx] = (g < N1 * DIN) ? lm_X[g] : 0.f;
    }
    const int z = tid & 31, jl = tid >> 5;
    float wk[DIN];
#pragma unroll
    for (int k = 0; k < DIN; ++k) wk[k] = Wk[z * DIN + k];
    __syncthreads();
#pragma unroll
    for (int q8 = 0; q8 < 8; ++q8) {
      const int jj = jl + q8 * 8;
      const int j = j0 + jj;
      float s = 0.f;
#pragma unroll
      for (int k = 0; k < DIN; ++k) s = fmaf(sX[jj * DIN + k], wk[k], s);
      float fval;
      if (z < DIN) fval = sX[jj * DIN + z];
      else fval = (j < N1) ? lm_Y[j * 2 + (z - DIN)] : 0.f;
      if (j < N1P) Kb[j * DZ + z] = (__bf16)s;
      sF[jj][z] = (__bf16)fval;
    }
    __syncthreads();
    const int z2 = tid >> 3, sub = tid & 7;
    const int jbase = j0 + sub * 8;
    if (jbase < N1P) {
      bf16x8 v;
#pragma unroll
      for (int e = 0; e < 8; ++e) v[e] = sF[sub * 8 + e][z2];
      *(bf16x8*)(Fzb + (size_t)z2 * N1P + jbase) = v;
    }
  } else if (bid < 236) {
    __shared__ float sX[64 * DIN];
    const int i0 = (bid - 157) * 64;
    for (int idx = tid; idx < 64 * DIN; idx += 256) {
      const int g = i0 * DIN + idx;
      sX[idx] = (g < N2 * DIN) ? tg_X[g] : 0.f;
    }
    const int z = tid & 31, il = tid >> 5;
    float wq[DIN];
#pragma unroll
    for (int k = 0; k < DIN; ++k) wq[k] = Wq[z * DIN + k];
    __syncthreads();
    const float rt = 0.17677669529663687f;  // 1/sqrt(32)
#pragma unroll
    for (int q8 = 0; q8 < 8; ++q8) {
      const int ii = il + q8 * 8;
      const int i = i0 + ii;
      float s = 0.f;
#pragma unroll
      for (int k = 0; k < DIN; ++k) s = fmaf(sX[ii * DIN + k], wq[k], s);
      if (i < N2P) Qb[i * DZ + z] = (__bf16)(s * rt);
    }
  } else {
    const int b3 = bid - 236;
    const int z = tid & 31, jg = tid >> 5;
    const float a = ap[0], b = bp[0], g1 = g1p[0];
    float rs = 0.f, dv = 0.f, dss = 0.f;
    for (int j = b3 * 8 + jg; j < N1; j += NRED * 8) {
      float f = (z < DIN) ? lm_X[j * DIN + z] : lm_Y[j * 2 + (z - DIN)];
      float ds = __expf(-g1 * (a * lm_delay[j] + b));
      rs += f; dv += ds * f;
      if (z == 0) dss += ds;
    }
    __shared__ float sb0[8][32], sb1[8][32], sd[8];
    sb0[jg][z] = rs; sb1[jg][z] = dv;
    if (z == 0) sd[jg] = dss;
    __syncthreads();
    if (tid < 32) {
      float t0 = 0.f, t1 = 0.f;
#pragma unroll
      for (int g = 0; g < 8; ++g) { t0 += sb0[g][tid]; t1 += sb1[g][tid]; }
      rp[b3 * 66 + tid] = t0;
      rp[b3 * 66 + 32 + tid] = t1;
    } else if (tid == 32) {
      float t = 0.f;
#pragma unroll
      for (int g = 0; g < 8; ++g) t += sd[g];
      rp[b3 * 66 + 64] = t;
    }
  }
}

// Single-pass attention. Per (i-tile, chunk-group) block: 4 waves = 4 j-chunks.
// x = (q/sqrt32)·k via MFMA; em1 = e^x-1 (deg-4 poly; zero pads -> em1=0 exactly);
// Zpart = sum em1; M1part = sum em1·F via MFMA.
__global__ __launch_bounds__(256) void k_attn(const __bf16* __restrict__ Kb,
    const __bf16* __restrict__ Fzb, const __bf16* __restrict__ Qb,
    float* __restrict__ Zp, __bf16* __restrict__ M1p) {
  __shared__ float sZ[4][32];
  __shared__ float sM[4][32][32];
  const int it = blockIdx.x / NCHB, cb = blockIdx.x % NCHB;
  const int i0 = it * 32;
  const int tid = threadIdx.x, lane = tid & 63, wid = tid >> 6;
  const int li = lane & 31, hi = lane >> 5;
  const int c = cb * 4 + wid;
  const int t0 = c * CTILES, t1 = min(t0 + CTILES, NTJ);
  const bf16x8 b0 = *(const bf16x8*)(Qb + (i0 + li) * DZ + hi * 8);
  const bf16x8 b1 = *(const bf16x8*)(Qb + (i0 + li) * DZ + 16 + hi * 8);
  const bool h = (hi != 0);
  const float C3 = 0.16666667f, C4 = 0.041666667f;
  float s1 = 0.f;
  f32x16 pacc = {0.f,0.f,0.f,0.f,0.f,0.f,0.f,0.f,0.f,0.f,0.f,0.f,0.f,0.f,0.f,0.f};
  for (int t = t0; t < t1; ++t) {
    const int jt = t * 32;
    bf16x8 a0 = *(const bf16x8*)(Kb + (jt + li) * DZ + hi * 8);
    bf16x8 a1 = *(const bf16x8*)(Kb + (jt + li) * DZ + 16 + hi * 8);
    bf16x8 fb0 = *(const bf16x8*)(Fzb + (size_t)li * N1P + jt + hi * 8);
    bf16x8 fb1 = *(const bf16x8*)(Fzb + (size_t)li * N1P + jt + 16 + hi * 8);
    f32x16 sacc = {0.f,0.f,0.f,0.f,0.f,0.f,0.f,0.f,0.f,0.f,0.f,0.f,0.f,0.f,0.f,0.f};
    sacc = __builtin_amdgcn_mfma_f32_32x32x16_bf16(a0, b0, sacc, 0, 0, 0);
    sacc = __builtin_amdgcn_mfma_f32_32x32x16_bf16(a1, b1, sacc, 0, 0, 0);
    float em1[16];
#pragma unroll
    for (int r = 0; r < 16; ++r) {
      const float x = sacc[r];
      float p = fmaf(x, C4, C3);
      p = fmaf(x, p, 0.5f);
      p = fmaf(x, p, 1.0f);
      const float e1 = x * p;     // e^x - 1, exact 0 for pad rows
      em1[r] = e1;
      s1 += e1;
    }
    unsigned u[8], pu[8];
#pragma unroll
    for (int k2 = 0; k2 < 8; ++k2) {
      u[k2] = pack2bf(em1[2 * k2], em1[2 * k2 + 1]);
      pu[k2] = __shfl_xor(u[k2], 32, 64);
    }
    W4 A1, A2;
    A1.w[0] = h ? pu[2] : u[0];
    A1.w[1] = h ? pu[3] : u[1];
    A1.w[2] = h ? u[2]  : pu[0];
    A1.w[3] = h ? u[3]  : pu[1];
    A2.w[0] = h ? pu[6] : u[4];
    A2.w[1] = h ? pu[7] : u[5];
    A2.w[2] = h ? u[6]  : pu[4];
    A2.w[3] = h ? u[7]  : pu[5];
    pacc = __builtin_amdgcn_mfma_f32_32x32x16_bf16(A1.v, fb0, pacc, 0, 0, 0);
    pacc = __builtin_amdgcn_mfma_f32_32x32x16_bf16(A2.v, fb1, pacc, 0, 0, 0);
  }
  s1 += __shfl_xor(s1, 32, 64);
  if (hi == 0) sZ[wid][li] = s1;
#pragma unroll
  for (int r = 0; r < 16; ++r) {
    const int irow = (r & 3) + 8 * (r >> 2) + 4 * hi;
    sM[wid][irow][li] = pacc[r];
  }
  __syncthreads();
  if (tid < 32)
    Zp[cb * N2P + i0 + tid] = sZ[0][tid] + sZ[1][tid] + sZ[2][tid] + sZ[3][tid];
#pragma unroll
  for (int v = 0; v < 4; ++v) {
    const int idx = v * 256 + tid;
    const int row = idx >> 5, z = idx & 31;
    float m = sM[0][row][z] + sM[1][row][z] + sM[2][row][z] + sM[3][row][z];
    M1p[((size_t)cb * N2P + i0 + row) * DZ + z] = (__bf16)m;
  }
}

// Tail: reduce red partials, inline router, per-target matvecs + heads.
__global__ __launch_bounds__(256) void k_final(
    const float* __restrict__ tg_X, const float* __restrict__ tg_delay,
    const float* __restrict__ Zp, const __bf16* __restrict__ M1p,
    const float* __restrict__ rp,
    const float* __restrict__ W1, const float* __restrict__ b1,
    const float* __restrict__ W2, const float* __restrict__ b2,
    const float* __restrict__ Wg, const float* __restrict__ bg,
    const float* __restrict__ Wa, const float* __restrict__ ba,
    const float* __restrict__ g2p, const float* __restrict__ g3p,
    const float* __restrict__ ap, const float* __restrict__ bp,
    float* __restrict__ out) {
  __shared__ float s_a[8][DZ], s_t1[8][DZ], s_t2[8][DZ];
  __shared__ float s_rsum[DZ], s_dv[DZ], s_r0[DZ], s_r1[DZ], s_tmp[DZ];
  __shared__ float s_ds[1];
  const int tid = threadIdx.x;
  const int z = tid & 31, li = tid >> 5;
  const int i = blockIdx.x * 8 + li;
  if (tid < 32) {
    float t0 = 0.f, t1 = 0.f;
#pragma unroll
    for (int cc = 0; cc < NRED; ++cc) {
      t0 += rp[cc * 66 + tid];
      t1 += rp[cc * 66 + 32 + tid];
    }
    s_rsum[tid] = t0; s_dv[tid] = t1;
  } else if (tid == 32) {
    float d = 0.f;
#pragma unroll
    for (int cc = 0; cc < NRED; ++cc) d += rp[cc * 66 + 64];
    s_ds[0] = d;
  }
  __syncthreads();
  if (li == 0) {
    const float r0 = s_rsum[z] * (1.f / (float)N1);
    s_r0[z] = r0;
    s_tmp[z] = (r0 + s_dv[z]) / (1.f + s_ds[0] + 1e-12f);
  }
  __syncthreads();
  if (li == 0) {
    float acc = b1[z];
#pragma unroll
    for (int k = 0; k < DZ; ++k) acc += W1[z * DZ + k] * s_tmp[k];
    s_r1[z] = acc;
  }
  const float a = ap[0], b = bp[0], g2 = g2p[0], g3 = g3p[0];
  const float td = tg_delay[i];
  const float rt0 = __expf(-g2 * (a * td + b));
  const float rt1 = __expf(-g3 * (a * td + b));
  const float tgx = (z < DIN) ? tg_X[i * DIN + z] : 0.f;
  float Zt = (float)N1, m1 = 0.f;
#pragma unroll
  for (int cc = 0; cc < NCHB; ++cc) {
    Zt += Zp[cc * N2P + i];
    m1 += (float)M1p[((size_t)cc * N2P + i) * DZ + z];
  }
  const float rsum_z = s_rsum[z];
  const float aggsum = rsum_z + (m1 + rsum_z) / Zt;   // sum_j t_j F_j
  const float sum_t = (float)N1 + 1.f;                // sum_j t_j
  const float deg = 1.f + sum_t + rt0 + 1e-12f;
  __syncthreads();
  s_a[li][z] = (tgx + aggsum + rt0 * s_r0[z]) / deg;
  __syncthreads();
  float t1 = b1[z];
#pragma unroll
  for (int k = 0; k < DZ; ++k) t1 += W1[z * DZ + k] * s_a[li][k];
  s_t1[li][z] = t1;
  __syncthreads();
  s_a[li][z] = (t1 + rt1 * s_r1[z]) / (1.f + rt1 + 1e-12f);
  __syncthreads();
  float t2 = b2[z];
#pragma unroll
  for (int k = 0; k < DZ; ++k) t2 += W2[z * DZ + k] * s_a[li][k];
  s_t2[li][z] = t2;
  __syncthreads();
  if (z < 5) {
    float og = bg[z];
#pragma unroll
    for (int k = 0; k < DZ; ++k) og += Wg[z * 64 + k] * s_t1[li][k];
#pragma unroll
    for (int k = 0; k < DZ; ++k) og += Wg[z * 64 + DZ + k] * s_t2[li][k];
    if (z == 0)      out[2 * i] = og;
    else if (z == 1) out[2 * i + 1] = og;
    else if (z == 2) out[10000 + i] = softplus_f(og);
    else if (z == 3) out[15000 + i] = softplus_f(og) + 1.f;
    else             out[20000 + i] = softplus_f(og);
  } else if (z >= 8 && z < 13) {
    const int hh = z - 8;
    float oa = ba[hh];
#pragma unroll
    for (int k = 0; k < DIN; ++k) oa += Wa[hh * DIN + k] * tg_X[i * DIN + k];
    if (hh == 0)      out[25000 + 2 * i] = oa;
    else if (hh == 1) out[25000 + 2 * i + 1] = oa;
    else if (hh == 2) out[35000 + i] = softplus_f(oa);
    else if (hh == 3) out[40000 + i] = softplus_f(oa) + 1.f;
    else              out[45000 + i] = softplus_f(oa);
  }
}

extern "C" void kernel_launch(void* const* d_in, const int* in_sizes, int n_in,
                              void* d_out, int out_size, void* d_ws, size_t ws_size,
                              hipStream_t stream) {
  const float* lm_X    = (const float*)d_in[0];
  const float* lm_Y    = (const float*)d_in[1];
  const float* tg_X    = (const float*)d_in[2];
  const float* lm_delay= (const float*)d_in[4];
  const float* tg_delay= (const float*)d_in[5];
  const float* Wq      = (const float*)d_in[6];
  const float* Wk      = (const float*)d_in[7];
  const float* g1      = (const float*)d_in[9];
  const float* g2      = (const float*)d_in[10];
  const float* g3      = (const float*)d_in[11];
  const float* al      = (const float*)d_in[12];
  const float* be      = (const float*)d_in[13];
  const float* W1      = (const float*)d_in[14];
  const float* b1      = (const float*)d_in[15];
  const float* W2      = (const float*)d_in[16];
  const float* b2      = (const float*)d_in[17];
  const float* Wg      = (const float*)d_in[18];
  const float* bg      = (const float*)d_in[19];
  const float* Wa      = (const float*)d_in[20];
  const float* ba      = (const float*)d_in[21];
  float* out = (float*)d_out;
  char* ws   = (char*)d_ws;

  __bf16* Kb   = (__bf16*)(ws + OFFB_K);
  __bf16* Fzb  = (__bf16*)(ws + OFFB_FZ);
  __bf16* Qb   = (__bf16*)(ws + OFFB_Q);
  float*  Zp   = (float*)(ws + OFFB_ZP);
  __bf16* M1p  = (__bf16*)(ws + OFFB_M1);
  float*  rp   = (float*)(ws + OFFB_RP);

  hipLaunchKernelGGL(k_prep, dim3(252), dim3(256), 0, stream,
                     lm_X, lm_Y, tg_X, lm_delay, Wq, Wk, g1, al, be,
                     Kb, Fzb, Qb, rp);
  hipLaunchKernelGGL(k_attn, dim3(NTI * NCHB), dim3(256), 0, stream,
                     Kb, Fzb, Qb, Zp, M1p);
  hipLaunchKernelGGL(k_final, dim3(625), dim3(256), 0, stream,
                     tg_X, tg_delay, Zp, M1p, rp,
                     W1, b1, W2, b2, Wg, bg, Wa, ba, g2, g3, al, be, out);
}